// Round 13
// baseline (261.196 us; speedup 1.0000x reference)
//
#include <hip/hip_runtime.h>
#include <math.h>

#define NB 2048
#define NF 42
#define NC 521
#define NROWS (NB * NF)   // 86016

// BRUX_COMBOS flattened: 13 combos x 3 (class, lo, hi)
__constant__ int   d_ccls[39] = {
    500, 41,  0,
    369, 500, 0,
    412, 431, 470,
    127, 67,  103,
    399, 403, 412,
    410, 411, 398,
    412, 410, 398,
    435, 438, 449,
    374, 436, 435,
    372, 434, 469,
    500, 439, 50,
    399, 403, 410,
    410, 398, 435};
__constant__ float d_clo[39] = {
    0.1f, 0.05f, 0.0f,
    0.1f, 0.1f,  0.0f,
    0.05f,0.05f, 0.05f,
    0.1f, 0.1f,  0.1f,
    0.1f, 0.1f,  0.1f,
    0.1f, 0.1f,  0.1f,
    0.1f, 0.1f,  0.1f,
    0.1f, 0.1f,  0.1f,
    0.1f, 0.1f,  0.1f,
    0.1f, 0.1f,  0.1f,
    0.1f, 0.1f,  0.1f,
    0.1f, 0.1f,  0.1f,
    0.1f, 0.1f,  0.1f};
__constant__ float d_chi[39] = {
    0.8f, 0.5f, 1.0f,
    0.5f, 0.5f, 1.0f,
    0.4f, 0.4f, 0.4f,
    0.8f, 0.7f, 0.6f,
    0.9f, 0.8f, 0.7f,
    0.9f, 0.8f, 0.7f,
    0.8f, 0.7f, 0.6f,
    0.9f, 0.8f, 0.7f,
    0.9f, 0.8f, 0.7f,
    0.9f, 0.8f, 0.7f,
    0.8f, 0.7f, 0.6f,
    0.9f, 0.8f, 0.7f,
    0.9f, 0.8f, 0.7f};
// round(score*100)/100 in f32 is identity for these constants
__constant__ float d_btab[13] = {2.94f, 1.76f, 1.76f, 1.47f, 0.29f, 0.88f, 0.01f,
                                 0.29f, 0.29f, 0.01f, 0.29f, 0.01f, 0.01f};

__device__ __forceinline__ float sel4(const float4& v, int e) {
    float r = v.x;
    r = (e == 1) ? v.y : r;
    r = (e == 2) ? v.z : r;
    r = (e == 3) ? v.w : r;
    return r;
}

// ---- kernel 1: one wave per (batch,frame) row; float4 stream via the aligned
// window [rowstart-p, rowstart-p+524), p = rowstart&3 (exact: 521*4+3 = 131*16B).
// 6 VMEM/row (3x dwordx4 + 3 gather dwords) instead of 12 scalar dwords.
__global__ __launch_bounds__(256, 8)
void frame_kernel(const float* __restrict__ score, float4* __restrict__ ws) {
    const int wave = threadIdx.x >> 6;
    const int lane = threadIdx.x & 63;
    const int gid  = blockIdx.x * 4 + wave;          // row id in [0, 86016)
    const size_t rowstart = (size_t)gid * NC;        // element index of row start
    const int p = (int)(rowstart & 3);               // phase: window head pad
    const float4* w4 = (const float4*)(score + (rowstart - p));  // 16B-aligned

    // 3 vector loads covering the whole row (+<=3 head, <=3 tail neighbors, masked)
    const float4 va = w4[lane];                          // j = 4*lane + i - p
    const float4 vb = w4[64 + lane];                     // j = 256 + 4*lane + i - p
    const float4 vc = w4[128 + (lane < 3 ? lane : 0)];   // j = 512 + 4*lane + i - p

    // combo gathers (hit lines already streamed)
    const int c3 = (lane < 13 ? lane : 0) * 3;
    const float* row = score + rowstart;
    const float a0 = row[d_ccls[c3 + 0]];
    const float a1 = row[d_ccls[c3 + 1]];
    const float a2 = row[d_ccls[c3 + 2]];

    // pivots j in {0,38,42} live in load A at lane (j+p)>>2, elem (j+p)&3 (uniform)
    const float v0  = __shfl(sel4(va,  p       & 3),  p       >> 2);
    const float v38 = __shfl(sel4(va, (38 + p) & 3), (38 + p) >> 2);
    const float v42 = __shfl(sel4(va, (42 + p) & 3), (42 + p) >> 2);

    // packed rank counters: rank0 | rank38<<10 | rank42<<20 (totals <= 521 < 1024)
    // full stable-tie predicate: v>vp || (v==vp && j<c)  (c=0 degenerates to v>v0)
    int cnt = 0;
    {   // A: j in [-3, 255] -> mask j>=0; tie region included
        const int jb = 4 * lane - p;
        const float vs[4] = {va.x, va.y, va.z, va.w};
#pragma unroll
        for (int i = 0; i < 4; ++i) {
            const int j = jb + i;
            const float v = vs[i];
            const int c = (int)(v > v0)
                        + ((int)((v > v38) || ((v == v38) && (j < 38))) << 10)
                        + ((int)((v > v42) || ((v == v42) && (j < 42))) << 20);
            cnt += (j >= 0) ? c : 0;
        }
    }
    {   // B: j in [253, 511] -> always valid, j > 42 so no tie-break
        const float vs[4] = {vb.x, vb.y, vb.z, vb.w};
#pragma unroll
        for (int i = 0; i < 4; ++i) {
            const float v = vs[i];
            cnt += (int)(v > v0) + ((int)(v > v38) << 10) + ((int)(v > v42) << 20);
        }
    }
    {   // C: j in [509, 523], only lanes<3 own real elements; mask j<521 too
        const int jb = 512 + 4 * lane - p;
        const float vs[4] = {vc.x, vc.y, vc.z, vc.w};
#pragma unroll
        for (int i = 0; i < 4; ++i) {
            const int j = jb + i;
            const float v = vs[i];
            const int c = (int)(v > v0) + ((int)(v > v38) << 10) + ((int)(v > v42) << 20);
            cnt += ((lane < 3) && (j < 521)) ? c : 0;
        }
    }
#pragma unroll
    for (int s = 32; s > 0; s >>= 1) cnt += __shfl_xor(cnt, s);

    const bool in0  = (cnt & 1023) < 10;             // rank<10 <=> in top-10 (stable)
    const bool in38 = ((cnt >> 10) & 1023) < 10;
    const bool in42 = ((cnt >> 20) & 1023) < 10;
    const bool has_nb = in0 || in38 || in42;

    bool pass = false;
    if (lane < 13) {                                  // guard: lanes>=13 hold lane-0 dups
        pass = (a0 >= d_clo[c3 + 0]) & (a0 <= d_chi[c3 + 0]) &
               (a1 >= d_clo[c3 + 1]) & (a1 <= d_chi[c3 + 1]) &
               (a2 >= d_clo[c3 + 2]) & (a2 <= d_chi[c3 + 2]);
    }
    const unsigned long long cm = __ballot(pass);
    const bool any   = (cm != 0ull);
    const int  first = any ? __builtin_ctzll(cm) : 0;

    const bool  bfj = any && !has_nb;
    const float bfs = bfj ? d_btab[first] : 0.0f;

    const bool  cpass = (v42 >= 0.1f) && (v42 <= 1.0f);
    const bool  cfj   = cpass || in42;
    const float cfs   = cpass ? 1.5f : (in42 ? 1.0f : 0.0f);

    if (lane == 0)
        ws[gid] = make_float4(bfj ? 1.0f : 0.0f, bfs, cfj ? 1.0f : 0.0f, cfs);
}

// ---- kernel 2: one wave per batch item; both window classifies in-register.
__global__ __launch_bounds__(256)
void group_kernel(const float4* __restrict__ ws, float* __restrict__ out) {
    const int wave = threadIdx.x >> 6;
    const int lane = threadIdx.x & 63;
    const int b    = blockIdx.x * 4 + wave;          // [0, 2048)

    float4 v = make_float4(0.0f, 0.0f, 0.0f, 0.0f);
    if (lane < NF) v = ws[b * NF + lane];
    const float bfj = v.x, bfs = v.y, cfj = v.z, cfs = v.w;

    // brux: gsize=4, R=39, min_valid=2, required=2
    {
        const float j1 = __shfl_down(bfj, 1), j2 = __shfl_down(bfj, 2), j3 = __shfl_down(bfj, 3);
        const float s1 = __shfl_down(bfs, 1), s2 = __shfl_down(bfs, 2), s3 = __shfl_down(bfs, 3);
        const float tc = ((bfj + j1) + j2) + j3;     // integral floats, exact
        const float ss = ((bfs + s1) + s2) + s3;     // same add order as reference window sum
        const bool  gj = (lane < 39) && (tc >= 2.0f);
        float gs = gj ? ss : -INFINITY;

        const unsigned long long jm = __ballot(gj);
        const bool ok = __popcll(jm) >= 2;
        float m1 = gs;
#pragma unroll
        for (int s = 32; s > 0; s >>= 1) m1 = fmaxf(m1, __shfl_xor(m1, s));
        const unsigned long long em = __ballot(gs == m1);
        const int amax = __builtin_ctzll(em);
        float m2 = (lane == amax) ? -INFINITY : gs;
#pragma unroll
        for (int s = 32; s > 0; s >>= 1) m2 = fmaxf(m2, __shfl_xor(m2, s));

        if (lane == 0) {
            out[b]      = ok ? 1.0f : 0.0f;
            out[NB + b] = ok ? (m1 + m2) : 0.0f;
        }
    }

    // cough: gsize=3, R=40, min_valid=2, required=2
    {
        const float j1 = __shfl_down(cfj, 1), j2 = __shfl_down(cfj, 2);
        const float s1 = __shfl_down(cfs, 1), s2 = __shfl_down(cfs, 2);
        const float tc = (cfj + j1) + j2;
        const float ss = (cfs + s1) + s2;
        const bool  gj = (lane < 40) && (tc >= 2.0f);
        float gs = gj ? ss : -INFINITY;

        const unsigned long long jm = __ballot(gj);
        const bool ok = __popcll(jm) >= 2;
        float m1 = gs;
#pragma unroll
        for (int s = 32; s > 0; s >>= 1) m1 = fmaxf(m1, __shfl_xor(m1, s));
        const unsigned long long em = __ballot(gs == m1);
        const int amax = __builtin_ctzll(em);
        float m2 = (lane == amax) ? -INFINITY : gs;
#pragma unroll
        for (int s = 32; s > 0; s >>= 1) m2 = fmaxf(m2, __shfl_xor(m2, s));

        if (lane == 0) {
            out[2 * NB + b] = ok ? 1.0f : 0.0f;
            out[3 * NB + b] = ok ? (m1 + m2) : 0.0f;
        }
    }
}

extern "C" void kernel_launch(void* const* d_in, const int* in_sizes, int n_in,
                              void* d_out, int out_size, void* d_ws, size_t ws_size,
                              hipStream_t stream) {
    const float* score = (const float*)d_in[0];
    float* out = (float*)d_out;
    float4* ws = (float4*)d_ws;                       // 86016 * 16B = 1.4 MB used
    frame_kernel<<<dim3(NROWS / 4), dim3(256), 0, stream>>>(score, ws);
    group_kernel<<<dim3(NB / 4), dim3(256), 0, stream>>>(ws, out);
}